// Round 3
// baseline (2434.424 us; speedup 1.0000x reference)
//
#include <hip/hip_runtime.h>
#include <math.h>

#define T_STEPS 512
#define HID 64

// ---- cross-lane helpers ----
__device__ __forceinline__ float dpp_xor1(float v) {
  return __int_as_float(__builtin_amdgcn_update_dpp(0, __float_as_int(v), 0xB1, 0xf, 0xf, true));
}
__device__ __forceinline__ float dpp_xor2(float v) {
  return __int_as_float(__builtin_amdgcn_update_dpp(0, __float_as_int(v), 0x4E, 0xf, 0xf, true));
}
__device__ __forceinline__ float swz_xor4(float v) {
  return __int_as_float(__builtin_amdgcn_ds_swizzle(__float_as_int(v), 0x101F));
}
// float2 acc: components = 2 batches. After reduction, lane holds the full
// 8-lane k-sum for batch beta = (lane&1).
__device__ __forceinline__ float qred8(const float2 a, bool beta) {
  float u = (beta ? a.y : a.x) + dpp_xor1(beta ? a.x : a.y);
  u += dpp_xor2(u);
  u += swz_xor4(u);
  return u;
}
__device__ __forceinline__ float sigm(float x) {
  return __builtin_amdgcn_rcpf(1.f + __expf(-x));
}
__device__ __forceinline__ float tanh_fast(float x) {
  return 1.f - 2.f * __builtin_amdgcn_rcpf(__expf(2.f * x) + 1.f);
}
__device__ __forceinline__ float gru_h(float r_, float z_, float in_, float hn_,
                                       float br, float bz, float bin, float bhn,
                                       float h) {
  const float r = sigm(r_ + br);
  const float z = sigm(z_ + bz);
  const float n = tanh_fast((in_ + bin) + r * (hn_ + bhn));
  return n + z * (h - n);
}

#define FMA2(acc, s, v) do { \
    acc.x = fmaf((s), (v).x, acc.x); \
    acc.y = fmaf((s), (v).y, acc.y); } while (0)

// LDS word for value V[k][b], b in {0,1}: chunks of 8 k (16 words) + 4 pad words.
// The 8 kq-group b128 broadcast reads start at words 20*kq8 (banks 0,20,8,28,16,4,24,12).
#define WRD(k, b) (20 * ((k) >> 3) + 2 * ((k) & 7) + (b))

// wi/wh: [row2][gate3][k8] flattened (row stride 24).
__device__ __forceinline__ void layer_acc(
    const float* __restrict__ ldsIn, const float* __restrict__ ldsSt,
    const float* __restrict__ wi, const float* __restrict__ wh,
    float2& r0, float2& z0, float2& n0, float2& g0,
    float2& r1, float2& z1, float2& n1, float2& g1)
{
  #pragma unroll
  for (int q = 0; q < 4; ++q) {
    const float4 xv = *(const float4*)(ldsIn + 4 * q);
    const float4 hv = *(const float4*)(ldsSt + 4 * q);
    const float2 x0 = make_float2(xv.x, xv.y), x1 = make_float2(xv.z, xv.w);
    const float2 h0 = make_float2(hv.x, hv.y), h1 = make_float2(hv.z, hv.w);
    const int k0 = 2 * q, k1 = 2 * q + 1;
    FMA2(r0, wi[k0], x0);      FMA2(r0, wi[k1], x1);
    FMA2(r0, wh[k0], h0);      FMA2(r0, wh[k1], h1);
    FMA2(z0, wi[8+k0], x0);    FMA2(z0, wi[8+k1], x1);
    FMA2(z0, wh[8+k0], h0);    FMA2(z0, wh[8+k1], h1);
    FMA2(n0, wi[16+k0], x0);   FMA2(n0, wi[16+k1], x1);
    FMA2(g0, wh[16+k0], h0);   FMA2(g0, wh[16+k1], h1);
    FMA2(r1, wi[24+k0], x0);   FMA2(r1, wi[24+k1], x1);
    FMA2(r1, wh[24+k0], h0);   FMA2(r1, wh[24+k1], h1);
    FMA2(z1, wi[32+k0], x0);   FMA2(z1, wi[32+k1], x1);
    FMA2(z1, wh[32+k0], h0);   FMA2(z1, wh[32+k1], h1);
    FMA2(n1, wi[40+k0], x0);   FMA2(n1, wi[40+k1], x1);
    FMA2(g1, wh[40+k0], h0);   FMA2(g1, wh[40+k1], h1);
  }
}

// WG = 256 threads (4 waves), B_wg = 2 batches, grid = 512 -> 2 independent WGs/CU.
// thread: g = tid>>3 owns rows 2g, 2g+1; kq8 = tid&7 owns k-chunk kq8*8..+7.
// Weights (192 floats) in registers; h/x round-trip through double-buffered LDS.
__global__ __launch_bounds__(256, 2) void gru_fused(
    const float* __restrict__ x,      // [1024][64][512]
    const float* __restrict__ Wih0, const float* __restrict__ Whh0,
    const float* __restrict__ bih0, const float* __restrict__ bhh0,
    const float* __restrict__ Wih1, const float* __restrict__ Whh1,
    const float* __restrict__ bih1, const float* __restrict__ bhh1,
    const float* __restrict__ W1, const float* __restrict__ b1,
    const float* __restrict__ W2, const float* __restrict__ b2,
    float* __restrict__ out)          // [1024][4]
{
  const int tid = threadIdx.x;
  const int g   = tid >> 3;
  const int kq8 = tid & 7;
  const bool beta = kq8 & 1;
  const int b0  = blockIdx.x << 1;

  __shared__ __align__(16) float xs_[2][160];
  __shared__ __align__(16) float hA_[2][160];
  __shared__ __align__(16) float hB_[2][160];
  __shared__ float msf[64];

  // ---- weights into registers ----
  float wiA[48], whA[48], wiB[48], whB[48];
  {
    const int kb = kq8 * 8;
    #pragma unroll
    for (int rr = 0; rr < 2; ++rr) {
      const int j = 2 * g + rr;
      #pragma unroll
      for (int gg = 0; gg < 3; ++gg) {
        #pragma unroll
        for (int q = 0; q < 2; ++q) {
          *(float4*)&wiA[rr*24 + gg*8 + 4*q] = *(const float4*)&Wih0[(j + 64*gg) * HID + kb + 4*q];
          *(float4*)&whA[rr*24 + gg*8 + 4*q] = *(const float4*)&Whh0[(j + 64*gg) * HID + kb + 4*q];
          *(float4*)&wiB[rr*24 + gg*8 + 4*q] = *(const float4*)&Wih1[(j + 64*gg) * HID + kb + 4*q];
          *(float4*)&whB[rr*24 + gg*8 + 4*q] = *(const float4*)&Whh1[(j + 64*gg) * HID + kb + 4*q];
        }
      }
    }
  }
  const int j0 = 2 * g, j1 = 2 * g + 1;
  const float bA0r = bih0[j0] + bhh0[j0],           bA1r = bih0[j1] + bhh0[j1];
  const float bA0z = bih0[j0+64] + bhh0[j0+64],     bA1z = bih0[j1+64] + bhh0[j1+64];
  const float bA0i = bih0[j0+128], bA0h = bhh0[j0+128];
  const float bA1i = bih0[j1+128], bA1h = bhh0[j1+128];
  const float bB0r = bih1[j0] + bhh1[j0],           bB1r = bih1[j1] + bhh1[j1];
  const float bB0z = bih1[j0+64] + bhh1[j0+64],     bB1z = bih1[j1+64] + bhh1[j1+64];
  const float bB0i = bih1[j0+128], bB0h = bhh1[j0+128];
  const float bB1i = bih1[j1+128], bB1h = bhh1[j1+128];

  const int rbase = 20 * kq8;                        // read base (words), 16B aligned
  const int wbase = 20 * (g >> 2) + 4 * (g & 3);     // write base: WRD(2g, 0)

  // x staging: tid<128, c = tid>>1, sb = tid&1
  const int sc = tid >> 1, sb = tid & 1;
  const float* xptr = x + ((size_t)(b0 + sb) * HID + sc) * T_STEPS;
  const int soff = WRD(sc, sb);

  float xpre = 0.f;
  if (tid < 128) {
    xs_[0][soff] = xptr[0];
    xpre = xptr[1];
  }
  for (int idx = tid; idx < 160; idx += 256) { hA_[0][idx] = 0.f; hB_[0][idx] = 0.f; }

  float hA0 = 0.f, hA1 = 0.f, hB0 = 0.f, hB1 = 0.f;  // lane's h[row0/1][batch beta]
  __syncthreads();

  #define ZF2 make_float2(0.f, 0.f)
  #define STEP(CUR, NXT, TT) do { \
      { float2 r0=ZF2, z0=ZF2, n0=ZF2, g0=ZF2, r1=ZF2, z1=ZF2, n1=ZF2, g1=ZF2; \
        layer_acc(&xs_[CUR][rbase], &hA_[CUR][rbase], wiA, whA, r0,z0,n0,g0,r1,z1,n1,g1); \
        hA0 = gru_h(qred8(r0,beta), qred8(z0,beta), qred8(n0,beta), qred8(g0,beta), \
                    bA0r, bA0z, bA0i, bA0h, hA0); \
        hA1 = gru_h(qred8(r1,beta), qred8(z1,beta), qred8(n1,beta), qred8(g1,beta), \
                    bA1r, bA1z, bA1i, bA1h, hA1); \
        if (kq8 < 2) { hA_[NXT][wbase + kq8] = hA0; hA_[NXT][wbase + 2 + kq8] = hA1; } } \
      __syncthreads(); \
      if (tid < 128) { \
        xs_[NXT][soff] = xpre; \
        if ((TT) < T_STEPS - 2) xpre = xptr[(TT) + 2]; \
      } \
      { float2 r0=ZF2, z0=ZF2, n0=ZF2, g0=ZF2, r1=ZF2, z1=ZF2, n1=ZF2, g1=ZF2; \
        layer_acc(&hA_[NXT][rbase], &hB_[CUR][rbase], wiB, whB, r0,z0,n0,g0,r1,z1,n1,g1); \
        hB0 = gru_h(qred8(r0,beta), qred8(z0,beta), qred8(n0,beta), qred8(g0,beta), \
                    bB0r, bB0z, bB0i, bB0h, hB0); \
        hB1 = gru_h(qred8(r1,beta), qred8(z1,beta), qred8(n1,beta), qred8(g1,beta), \
                    bB1r, bB1z, bB1i, bB1h, hB1); \
        if (kq8 < 2) { hB_[NXT][wbase + kq8] = hB0; hB_[NXT][wbase + 2 + kq8] = hB1; } } \
      __syncthreads(); \
    } while (0)

  #pragma unroll 1
  for (int t = 0; t < T_STEPS; t += 2) {
    STEP(0, 1, t);
    STEP(1, 0, t + 1);
  }
  #undef STEP

  // final hB(t=511) is in hB_[0]
  if (tid < 64) {
    const int bb = tid >> 5, u = tid & 31;
    float acc = b1[u];
    const float* w1r = W1 + u * HID;
    #pragma unroll
    for (int k = 0; k < 64; ++k)
      acc = fmaf(w1r[k], hB_[0][WRD(k, bb)], acc);
    msf[(bb << 5) + u] = fmaxf(acc, 0.f);
  }
  __syncthreads();
  if (tid < 8) {
    const int bb = tid >> 2, c = tid & 3;
    float acc = b2[c];
    const float* w2r = W2 + (c << 5);
    #pragma unroll
    for (int u = 0; u < 32; ++u)
      acc = fmaf(w2r[u], msf[(bb << 5) + u], acc);
    out[(size_t)(b0 + bb) * 4 + c] = acc;
  }
}

extern "C" void kernel_launch(void* const* d_in, const int* in_sizes, int n_in,
                              void* d_out, int out_size, void* d_ws, size_t ws_size,
                              hipStream_t stream) {
  const float* x    = (const float*)d_in[0];
  const float* Wih0 = (const float*)d_in[1];
  const float* Whh0 = (const float*)d_in[2];
  const float* bih0 = (const float*)d_in[3];
  const float* bhh0 = (const float*)d_in[4];
  const float* Wih1 = (const float*)d_in[5];
  const float* Whh1 = (const float*)d_in[6];
  const float* bih1 = (const float*)d_in[7];
  const float* bhh1 = (const float*)d_in[8];
  const float* W1   = (const float*)d_in[9];
  const float* b1   = (const float*)d_in[10];
  const float* W2   = (const float*)d_in[11];
  const float* b2   = (const float*)d_in[12];
  float* out = (float*)d_out;

  hipLaunchKernelGGL(gru_fused, dim3(512), dim3(256), 0, stream,
                     x, Wih0, Whh0, bih0, bhh0, Wih1, Whh1, bih1, bhh1,
                     W1, b1, W2, b2, out);
}

// Round 4
// 943.207 us; speedup vs baseline: 2.5810x; 2.5810x over previous
//
#include <hip/hip_runtime.h>

#define T_STEPS 512
#define HID 64

typedef short bf16x8 __attribute__((ext_vector_type(8)));
typedef float f32x4 __attribute__((ext_vector_type(4)));

__device__ __forceinline__ float sigm(float x) {
  return __builtin_amdgcn_rcpf(1.f + __expf(-x));
}
__device__ __forceinline__ float tanh_fast(float x) {
  return 1.f - 2.f * __builtin_amdgcn_rcpf(__expf(2.f * x) + 1.f);
}

// Split 8 consecutive fp32 at p into bf16 hi (chop) + bf16 lo (chop of exact residual).
// v = hi + lo + O(2^-16 |v|). bf16 shares fp32 exponent range -> lo never denormal.
__device__ __forceinline__ void split8(const float* __restrict__ p, bf16x8& hi, bf16x8& lo) {
  float v[8];
  *(float4*)&v[0] = *(const float4*)p;
  *(float4*)&v[4] = *(const float4*)(p + 4);
  #pragma unroll
  for (int i = 0; i < 8; ++i) {
    unsigned u = __float_as_uint(v[i]);
    float r = v[i] - __uint_as_float(u & 0xffff0000u);   // exact in fp32
    hi[i] = (short)(u >> 16);
    lo[i] = (short)(__float_as_uint(r) >> 16);
  }
}

#define MM(acc, A, B) acc = __builtin_amdgcn_mfma_f32_16x16x32_bf16((A), (B), (acc), 0, 0, 0)

// K-concat 6-chunk accumulation: Wh*vh (2 chunks) + Wh*vl + Wl*vh
#define GATE6(acc, IH0, IH1, IL0, IL1, NM) do { \
    MM(acc, IH0, NM##h0); MM(acc, IH1, NM##h1); \
    MM(acc, IL0, NM##h0); MM(acc, IL1, NM##h1); \
    MM(acc, IH0, NM##l0); MM(acc, IH1, NM##l1); } while (0)

// Declare + load one weight B-fragment set (hi/lo x 2 K-chunks) for gate row-block goff.
// B[k][n] = W[j = 16*wv + (lane&15)][k], lane reads 8 consecutive k at quad*8 (+32c).
#define WFRAG(NM, Wp, goff) \
  bf16x8 NM##h0, NM##l0, NM##h1, NM##l1; \
  split8((Wp) + (goff) * (64 * HID) + wrowoff, NM##h0, NM##l0); \
  split8((Wp) + (goff) * (64 * HID) + wrowoff + 32, NM##h1, NM##l1)

// Grid 256 x WG 256 (4 waves). WG owns batches b0..b0+3 (M-rows 0-3; rows 4-15 zero).
// Wave w owns output slice j in [16w, 16w+16) (one N-tile) for both layers.
// LDS x/h: [m=batch row (16)][k (64)] with row stride 68 (2-way bank alias only).
__global__ __launch_bounds__(256, 1) void gru_mfma(
    const float* __restrict__ x,
    const float* __restrict__ Wih0, const float* __restrict__ Whh0,
    const float* __restrict__ bih0, const float* __restrict__ bhh0,
    const float* __restrict__ Wih1, const float* __restrict__ Whh1,
    const float* __restrict__ bih1, const float* __restrict__ bhh1,
    const float* __restrict__ W1, const float* __restrict__ b1,
    const float* __restrict__ W2, const float* __restrict__ b2,
    float* __restrict__ out)
{
  const int tid  = threadIdx.x;
  const int lane = tid & 63;
  const int wv   = tid >> 6;
  const int nloc = lane & 15;
  const int quad = lane >> 4;
  const int b0   = blockIdx.x << 2;

  __shared__ __align__(16) float xs[1088];
  __shared__ __align__(16) float hA[1088];
  __shared__ __align__(16) float hB[1088];
  __shared__ float msf[128];

  // ---- weight B-fragments into registers (AGPR-backed; 48 frags = 192 regs) ----
  const int wrowoff = (16 * wv + nloc) * HID + 8 * quad;
  WFRAG(i0r, Wih0, 0); WFRAG(i0z, Wih0, 1); WFRAG(i0n, Wih0, 2);
  WFRAG(h0r, Whh0, 0); WFRAG(h0z, Whh0, 1); WFRAG(h0n, Whh0, 2);
  WFRAG(i1r, Wih1, 0); WFRAG(i1z, Wih1, 1); WFRAG(i1n, Wih1, 2);
  WFRAG(h1r, Whh1, 0); WFRAG(h1z, Whh1, 1); WFRAG(h1n, Whh1, 2);

  const int jg = 16 * wv + nloc;
  const float bA_r = bih0[jg] + bhh0[jg];
  const float bA_z = bih0[jg + 64] + bhh0[jg + 64];
  const float bA_i = bih0[jg + 128], bA_h = bhh0[jg + 128];
  const float bB_r = bih1[jg] + bhh1[jg];
  const float bB_z = bih1[jg + 64] + bhh1[jg + 64];
  const float bB_i = bih1[jg + 128], bB_h = bhh1[jg + 128];

  // x staging: thread (wv = batch row, lane = channel) loads x[b0+wv][lane][t]
  const float* xptr = x + ((size_t)(b0 + wv) * HID + lane) * T_STEPS;
  const int soff = wv * 68 + lane;

  float xfirst = xptr[0];
  for (int i = tid; i < 1088; i += 256) {
    hA[i] = 0.f; hB[i] = 0.f;
    if (i >= 272) xs[i] = 0.f;      // rows 4-15 of xs stay zero forever
  }
  xs[soff] = xfirst;                // rows 0-3 (disjoint from zeroed region)
  __syncthreads();

  const int abase = nloc * 68 + 8 * quad;   // A-frag read base: A[m=lane&15][k=quad*8 (+32c)]
  bf16x8 XH0, XH1, XL0, XL1;
  split8(&xs[abase], XH0, XL0);
  split8(&xs[abase + 32], XH1, XL1);
  bf16x8 AH0 = {0,0,0,0,0,0,0,0}, AH1 = AH0, AL0 = AH0, AL1 = AH0;
  bf16x8 BH0 = AH0, BH1 = AH0, BL0 = AH0, BL1 = AH0;

  float hpa[4] = {0.f, 0.f, 0.f, 0.f};
  float hpb[4] = {0.f, 0.f, 0.f, 0.f};

  #pragma unroll 1
  for (int t = 0; t < T_STEPS; ++t) {
    float xnext = (t < T_STEPS - 1) ? xptr[t + 1] : 0.f;

    // ---- layer 0: 36 mfma ----
    f32x4 aR = {0,0,0,0}, aZ = {0,0,0,0}, aI = {0,0,0,0}, aH = {0,0,0,0};
    GATE6(aR, XH0, XH1, XL0, XL1, i0r);
    GATE6(aZ, XH0, XH1, XL0, XL1, i0z);
    GATE6(aI, XH0, XH1, XL0, XL1, i0n);
    GATE6(aR, AH0, AH1, AL0, AL1, h0r);
    GATE6(aZ, AH0, AH1, AL0, AL1, h0z);
    GATE6(aH, AH0, AH1, AL0, AL1, h0n);

    if (lane < 16) {   // C rows 0-3 live in quad 0, regs 0-3
      #pragma unroll
      for (int q = 0; q < 4; ++q) {
        float r = sigm(aR[q] + bA_r);
        float z = sigm(aZ[q] + bA_z);
        float n = tanh_fast((aI[q] + bA_i) + r * (aH[q] + bA_h));
        float h = n + z * (hpa[q] - n);
        hpa[q] = h;
        hA[q * 68 + jg] = h;
      }
    }
    __syncthreads();                       // b1: hA(t) visible; xs(t) frags already consumed
    xs[soff] = xnext;                      // stage x(t+1); read only after b2
    split8(&hA[abase], AH0, AL0);          // hA(t) frags: layer-1 input AND next step's state
    split8(&hA[abase + 32], AH1, AL1);

    // ---- layer 1: 36 mfma ----
    f32x4 cR = {0,0,0,0}, cZ = {0,0,0,0}, cI = {0,0,0,0}, cH = {0,0,0,0};
    GATE6(cR, AH0, AH1, AL0, AL1, i1r);
    GATE6(cZ, AH0, AH1, AL0, AL1, i1z);
    GATE6(cI, AH0, AH1, AL0, AL1, i1n);
    GATE6(cR, BH0, BH1, BL0, BL1, h1r);
    GATE6(cZ, BH0, BH1, BL0, BL1, h1z);
    GATE6(cH, BH0, BH1, BL0, BL1, h1n);

    if (lane < 16) {
      #pragma unroll
      for (int q = 0; q < 4; ++q) {
        float r = sigm(cR[q] + bB_r);
        float z = sigm(cZ[q] + bB_z);
        float n = tanh_fast((cI[q] + bB_i) + r * (cH[q] + bB_h));
        float h = n + z * (hpb[q] - n);
        hpb[q] = h;
        hB[q * 68 + jg] = h;
      }
    }
    __syncthreads();                       // b2: hB(t) + xs(t+1) visible
    split8(&hB[abase], BH0, BL0);
    split8(&hB[abase + 32], BH1, BL1);
    split8(&xs[abase], XH0, XL0);
    split8(&xs[abase + 32], XH1, XL1);
  }

  // ---- classifier on hB(T-1) (in LDS, rows 0-3) ----
  if (tid < 128) {
    const int bb = tid >> 5, u = tid & 31;
    float acc = b1[u];
    const float* w1r = W1 + u * HID;
    #pragma unroll
    for (int k = 0; k < 64; ++k)
      acc = fmaf(w1r[k], hB[bb * 68 + k], acc);
    msf[(bb << 5) + u] = fmaxf(acc, 0.f);
  }
  __syncthreads();
  if (tid < 16) {
    const int bb = tid >> 2, c = tid & 3;
    float acc = b2[c];
    const float* w2r = W2 + (c << 5);
    #pragma unroll
    for (int u = 0; u < 32; ++u)
      acc = fmaf(w2r[u], msf[(bb << 5) + u], acc);
    out[(size_t)(b0 + bb) * 4 + c] = acc;
  }
}

extern "C" void kernel_launch(void* const* d_in, const int* in_sizes, int n_in,
                              void* d_out, int out_size, void* d_ws, size_t ws_size,
                              hipStream_t stream) {
  const float* x    = (const float*)d_in[0];
  const float* Wih0 = (const float*)d_in[1];
  const float* Whh0 = (const float*)d_in[2];
  const float* bih0 = (const float*)d_in[3];
  const float* bhh0 = (const float*)d_in[4];
  const float* Wih1 = (const float*)d_in[5];
  const float* Whh1 = (const float*)d_in[6];
  const float* bih1 = (const float*)d_in[7];
  const float* bhh1 = (const float*)d_in[8];
  const float* W1   = (const float*)d_in[9];
  const float* b1   = (const float*)d_in[10];
  const float* W2   = (const float*)d_in[11];
  const float* b2   = (const float*)d_in[12];
  float* out = (float*)d_out;

  hipLaunchKernelGGL(gru_mfma, dim3(256), dim3(256), 0, stream,
                     x, Wih0, Whh0, bih0, bhh0, Wih1, Whh1, bih1, bhh1,
                     W1, b1, W2, b2, out);
}

// Round 5
// 595.855 us; speedup vs baseline: 4.0856x; 1.5829x over previous
//
#include <hip/hip_runtime.h>

#define T_STEPS 512
#define HID 64

typedef short bf16x8 __attribute__((ext_vector_type(8)));
typedef float f32x4 __attribute__((ext_vector_type(4)));

__device__ __forceinline__ float sigm(float x) {
  return __builtin_amdgcn_rcpf(1.f + __expf(-x));
}
__device__ __forceinline__ float tanh_fast(float x) {
  return 1.f - 2.f * __builtin_amdgcn_rcpf(__expf(2.f * x) + 1.f);
}

// split fp32 -> bf16 hi (chop) + bf16 lo (chop of exact residual)
__device__ __forceinline__ void split1(float v, short* hi, short* lo) {
  unsigned u = __float_as_uint(v);
  float r = v - __uint_as_float(u & 0xffff0000u);   // exact in fp32
  *hi = (short)(u >> 16);
  *lo = (short)(__float_as_uint(r) >> 16);
}

__device__ __forceinline__ void split8(const float* __restrict__ p, bf16x8& hi, bf16x8& lo) {
  float v[8];
  *(float4*)&v[0] = *(const float4*)p;
  *(float4*)&v[4] = *(const float4*)(p + 4);
  #pragma unroll
  for (int i = 0; i < 8; ++i) {
    unsigned u = __float_as_uint(v[i]);
    float r = v[i] - __uint_as_float(u & 0xffff0000u);
    hi[i] = (short)(u >> 16);
    lo[i] = (short)(__float_as_uint(r) >> 16);
  }
}

#define MM(acc, A, B) acc = __builtin_amdgcn_mfma_f32_16x16x32_bf16((A), (B), (acc), 0, 0, 0)

// K-concat 6-chunk accumulation: Wh*vh (2 chunks) + Wh*vl + Wl*vh
#define GATE6(acc, IH0, IH1, IL0, IL1, NM) do { \
    MM(acc, IH0, NM##h0); MM(acc, IH1, NM##h1); \
    MM(acc, IL0, NM##h0); MM(acc, IL1, NM##h1); \
    MM(acc, IH0, NM##l0); MM(acc, IH1, NM##l1); } while (0)

#define WFRAG(NM, Wp, goff) \
  bf16x8 NM##h0, NM##l0, NM##h1, NM##l1; \
  split8((Wp) + (goff) * (64 * HID) + wrowoff, NM##h0, NM##l0); \
  split8((Wp) + (goff) * (64 * HID) + wrowoff + 32, NM##h1, NM##l1)

// LDS A-matrices: logical [m(16)][k(64)] bf16, stored XOR-swizzled in 16B units:
// element idx (shorts) = m*64 + (((k>>3) ^ (m&7))<<3) + (k&7).
// Fragment read (chunk c, lane (nloc,quad)): base = nloc*64 + (((c*4+quad)^(nloc&7))<<3)
// -> 64 lanes hit all 8 bank-quads uniformly (8 lanes each): conflict-free b128.
// Batches live at rows m = 4*b; other rows stay zero forever.
__global__ __launch_bounds__(256, 1) void gru_mfma(
    const float* __restrict__ x,
    const float* __restrict__ Wih0, const float* __restrict__ Whh0,
    const float* __restrict__ bih0, const float* __restrict__ bhh0,
    const float* __restrict__ Wih1, const float* __restrict__ Whh1,
    const float* __restrict__ bih1, const float* __restrict__ bhh1,
    const float* __restrict__ W1, const float* __restrict__ b1,
    const float* __restrict__ W2, const float* __restrict__ b2,
    float* __restrict__ out)
{
  const int tid  = threadIdx.x;
  const int lane = tid & 63;
  const int wv   = tid >> 6;
  const int nloc = lane & 15;
  const int quad = lane >> 4;
  const int b0   = blockIdx.x << 2;

  __shared__ __align__(16) short xsH[1024], xsL[1024];
  __shared__ __align__(16) short hAH[1024], hAL[1024];
  __shared__ __align__(16) short hBH[1024], hBL[1024];
  __shared__ float hfin[256];
  __shared__ float msf[128];

  // ---- weight B-fragments (unchanged from R4; verified layout) ----
  const int wrowoff = (16 * wv + nloc) * HID + 8 * quad;
  WFRAG(i0r, Wih0, 0); WFRAG(i0z, Wih0, 1); WFRAG(i0n, Wih0, 2);
  WFRAG(h0r, Whh0, 0); WFRAG(h0z, Whh0, 1); WFRAG(h0n, Whh0, 2);
  WFRAG(i1r, Wih1, 0); WFRAG(i1z, Wih1, 1); WFRAG(i1n, Wih1, 2);
  WFRAG(h1r, Whh1, 0); WFRAG(h1z, Whh1, 1); WFRAG(h1n, Whh1, 2);

  const int jg = 16 * wv + nloc;
  const float bA_r = bih0[jg] + bhh0[jg];
  const float bA_z = bih0[jg + 64] + bhh0[jg + 64];
  const float bA_i = bih0[jg + 128], bA_h = bhh0[jg + 128];
  const float bB_r = bih1[jg] + bhh1[jg];
  const float bB_z = bih1[jg + 64] + bhh1[jg + 64];
  const float bB_i = bih1[jg + 128], bB_h = bhh1[jg + 128];

  // loop-invariant LDS indices (shorts)
  const int ra0 = nloc * 64 + (((quad    ) ^ (nloc & 7)) << 3);
  const int ra1 = nloc * 64 + (((quad + 4) ^ (nloc & 7)) << 3);
  const int hwr = quad * 256 + (((jg >> 3) ^ ((quad & 1) << 2)) << 3) + (jg & 7);
  const int xwr = wv * 256 + (((lane >> 3) ^ ((wv & 1) << 2)) << 3) + (lane & 7);

  const float* xptr = x + ((size_t)(b0 + wv) * HID + lane) * T_STEPS;
  float xfirst = xptr[0];

  for (int i = tid; i < 1024; i += 256) {
    xsH[i] = 0; xsL[i] = 0; hAH[i] = 0; hAL[i] = 0; hBH[i] = 0; hBL[i] = 0;
  }
  __syncthreads();
  { short h, l; split1(xfirst, &h, &l); xsH[xwr] = h; xsL[xwr] = l; }
  __syncthreads();

  bf16x8 XH0 = *(const bf16x8*)&xsH[ra0], XH1 = *(const bf16x8*)&xsH[ra1];
  bf16x8 XL0 = *(const bf16x8*)&xsL[ra0], XL1 = *(const bf16x8*)&xsL[ra1];
  bf16x8 AH0 = {0,0,0,0,0,0,0,0}, AH1 = AH0, AL0 = AH0, AL1 = AH0;
  bf16x8 BH0 = AH0, BH1 = AH0, BL0 = AH0, BL1 = AH0;

  float hpa = 0.f, hpb = 0.f;   // lane's h[batch=quad][j=jg]

  #pragma unroll 1
  for (int t = 0; t < T_STEPS; ++t) {
    float xnext = (t < T_STEPS - 1) ? xptr[t + 1] : 0.f;

    // ---- layer 0 (h-gates first: operands long-ready) ----
    f32x4 aR = {0,0,0,0}, aZ = {0,0,0,0}, aI = {0,0,0,0}, aH = {0,0,0,0};
    GATE6(aR, AH0, AH1, AL0, AL1, h0r);
    GATE6(aZ, AH0, AH1, AL0, AL1, h0z);
    GATE6(aH, AH0, AH1, AL0, AL1, h0n);
    GATE6(aR, XH0, XH1, XL0, XL1, i0r);
    GATE6(aZ, XH0, XH1, XL0, XL1, i0z);
    GATE6(aI, XH0, XH1, XL0, XL1, i0n);
    {
      float r = sigm(aR[0] + bA_r);
      float z = sigm(aZ[0] + bA_z);
      float n = tanh_fast((aI[0] + bA_i) + r * (aH[0] + bA_h));
      hpa = n + z * (hpa - n);
      short h, l; split1(hpa, &h, &l);
      hAH[hwr] = h; hAL[hwr] = l;
    }
    __syncthreads();                                  // b1: hA(t) visible
    AH0 = *(const bf16x8*)&hAH[ra0]; AH1 = *(const bf16x8*)&hAH[ra1];
    AL0 = *(const bf16x8*)&hAL[ra0]; AL1 = *(const bf16x8*)&hAL[ra1];

    // ---- layer 1 (h-gates on old B-frags issue under the hA read latency) ----
    f32x4 cR = {0,0,0,0}, cZ = {0,0,0,0}, cI = {0,0,0,0}, cH = {0,0,0,0};
    GATE6(cR, BH0, BH1, BL0, BL1, h1r);
    GATE6(cZ, BH0, BH1, BL0, BL1, h1z);
    GATE6(cH, BH0, BH1, BL0, BL1, h1n);
    GATE6(cR, AH0, AH1, AL0, AL1, i1r);
    GATE6(cZ, AH0, AH1, AL0, AL1, i1z);
    GATE6(cI, AH0, AH1, AL0, AL1, i1n);
    {
      float r = sigm(cR[0] + bB_r);
      float z = sigm(cZ[0] + bB_z);
      float n = tanh_fast((cI[0] + bB_i) + r * (cH[0] + bB_h));
      hpb = n + z * (hpb - n);
      short h, l; split1(hpb, &h, &l);
      hBH[hwr] = h; hBL[hwr] = l;
    }
    { short h, l; split1(xnext, &h, &l); xsH[xwr] = h; xsL[xwr] = l; }
    if (t == T_STEPS - 1) hfin[quad * 64 + jg] = hpb;
    __syncthreads();                                  // b2: hB(t), xs(t+1) visible
    BH0 = *(const bf16x8*)&hBH[ra0]; BH1 = *(const bf16x8*)&hBH[ra1];
    BL0 = *(const bf16x8*)&hBL[ra0]; BL1 = *(const bf16x8*)&hBL[ra1];
    XH0 = *(const bf16x8*)&xsH[ra0]; XH1 = *(const bf16x8*)&xsH[ra1];
    XL0 = *(const bf16x8*)&xsL[ra0]; XL1 = *(const bf16x8*)&xsL[ra1];
  }

  // ---- classifier on hfin = hB(T-1), fp32 ----
  if (tid < 128) {
    const int bb = tid >> 5, u = tid & 31;
    float acc = b1[u];
    const float* w1r = W1 + u * HID;
    #pragma unroll
    for (int k = 0; k < 64; ++k)
      acc = fmaf(w1r[k], hfin[bb * 64 + k], acc);
    msf[(bb << 5) + u] = fmaxf(acc, 0.f);
  }
  __syncthreads();
  if (tid < 16) {
    const int bb = tid >> 2, c = tid & 3;
    float acc = b2[c];
    const float* w2r = W2 + (c << 5);
    #pragma unroll
    for (int u = 0; u < 32; ++u)
      acc = fmaf(w2r[u], msf[(bb << 5) + u], acc);
    out[(size_t)(b0 + bb) * 4 + c] = acc;
  }
}

extern "C" void kernel_launch(void* const* d_in, const int* in_sizes, int n_in,
                              void* d_out, int out_size, void* d_ws, size_t ws_size,
                              hipStream_t stream) {
  const float* x    = (const float*)d_in[0];
  const float* Wih0 = (const float*)d_in[1];
  const float* Whh0 = (const float*)d_in[2];
  const float* bih0 = (const float*)d_in[3];
  const float* bhh0 = (const float*)d_in[4];
  const float* Wih1 = (const float*)d_in[5];
  const float* Whh1 = (const float*)d_in[6];
  const float* bih1 = (const float*)d_in[7];
  const float* bhh1 = (const float*)d_in[8];
  const float* W1   = (const float*)d_in[9];
  const float* b1   = (const float*)d_in[10];
  const float* W2   = (const float*)d_in[11];
  const float* b2   = (const float*)d_in[12];
  float* out = (float*)d_out;

  hipLaunchKernelGGL(gru_mfma, dim3(256), dim3(256), 0, stream,
                     x, Wih0, Whh0, bih0, bhh0, Wih1, Whh1, bih1, bhh1,
                     W1, b1, W2, b2, out);
}